// Round 10
// baseline (30038.861 us; speedup 1.0000x reference)
//
#include <hip/hip_runtime.h>
#include <hip/hip_cooperative_groups.h>
#include <math.h>

namespace cg = cooperative_groups;

constexpr int kB = 64, kS = 24, kT = 96, kE = 256, kH = 512, kA = 512;
constexpr int NWG = 256, NTH = 512;
constexpr int NG = 8, GWG = 32, GB = 8;   // groups, WGs/group, batches/group
constexpr int WHP = 516;   // whh LDS row stride
constexpr int HSP = 580;   // hstage/parts row stride
constexpr int EMP = 264;   // embed LDS row stride
constexpr int EMB0 = 4640; // embed base inside uni
constexpr int ATP = 516;   // attention staging stride

// ws layout (floats)
constexpr int OFF_PUB = 0;                       // [2][NG][GWG*128] = 65536
constexpr int OFF_SH  = OFF_PUB + 2 * NG * GWG * 128;
constexpr int OFF_HS  = OFF_SH + 2 * kB * kH;
constexpr int OFF_Z   = OFF_HS + kB * kT * kH;
constexpr int OFF_CTX = OFF_Z + kB * kT;
constexpr int OFF_SHS = OFF_CTX + kB * kH;
constexpr int OFF_Z2  = OFF_SHS + kB * kS * kH;
constexpr int OFF_FLG = (OFF_Z2 + kB * kS + 31) & ~31;
// flag block (uints): [0,8192) flags; [8192,8448) cnt; [8448,8704) tst flag;
// [8704,8960) tst data; [8960,9216) verdicts

typedef float f4v __attribute__((ext_vector_type(4)));

__device__ __forceinline__ float sigmoidf(float x) { return 1.0f / (1.0f + expf(-x)); }
__device__ __forceinline__ float dot4(float4 a, float4 b) {
  return a.x * b.x + a.y * b.y + a.z * b.z + a.w * b.w;
}
// ---- agent-scope (MALL) ops ----
__device__ __forceinline__ float2 aload2(const float* p) {
  unsigned long long u = __hip_atomic_load((const unsigned long long*)p,
                                           __ATOMIC_RELAXED, __HIP_MEMORY_SCOPE_AGENT);
  union { unsigned long long u; float2 f; } cv; cv.u = u;
  return cv.f;
}
__device__ __forceinline__ float aload1(const float* p) {
  return __hip_atomic_load(p, __ATOMIC_RELAXED, __HIP_MEMORY_SCOPE_AGENT);
}
__device__ __forceinline__ void astore(float* p, float v) {
  __hip_atomic_store(p, v, __ATOMIC_RELAXED, __HIP_MEMORY_SCOPE_AGENT);
}
__device__ __forceinline__ unsigned aloadu(const unsigned* p) {
  return __hip_atomic_load(p, __ATOMIC_RELAXED, __HIP_MEMORY_SCOPE_AGENT);
}
__device__ __forceinline__ void astoreu(unsigned* p, unsigned v) {
  __hip_atomic_store(p, v, __ATOMIC_RELAXED, __HIP_MEMORY_SCOPE_AGENT);
}
// ---- L2-scope (intra-XCD) ops: bypass L1 (sc0), served by local L2 ----
__device__ __forceinline__ unsigned l2_loadu(const unsigned* p) {
  unsigned r;
  asm volatile("global_load_dword %0, %1, off sc0\n\ts_waitcnt vmcnt(0)"
               : "=v"(r) : "v"(p) : "memory");
  return r;
}
__device__ __forceinline__ float l2_load1(const float* p) {
  float r;
  asm volatile("global_load_dword %0, %1, off sc0\n\ts_waitcnt vmcnt(0)"
               : "=v"(r) : "v"(p) : "memory");
  return r;
}
__device__ __forceinline__ float2 l2_load2(const float* p) {
  float2 r;
  asm volatile("global_load_dwordx2 %0, %1, off sc0\n\ts_waitcnt vmcnt(0)"
               : "=v"(r) : "v"(p) : "memory");
  return r;
}
__device__ __forceinline__ void l2_load8(const float* p, f4v& a, f4v& b) {
  asm volatile("global_load_dwordx4 %0, %2, off sc0\n\t"
               "global_load_dwordx4 %1, %2, off offset:16 sc0\n\t"
               "s_waitcnt vmcnt(0)"
               : "=&v"(a), "=&v"(b) : "v"(p) : "memory");
}
__device__ __forceinline__ void l2_load4s(const float* p0, const float* p1,
                                          const float* p2, const float* p3,
                                          float& r0, float& r1, float& r2, float& r3) {
  asm volatile("global_load_dword %0, %4, off sc0\n\t"
               "global_load_dword %1, %5, off sc0\n\t"
               "global_load_dword %2, %6, off sc0\n\t"
               "global_load_dword %3, %7, off sc0\n\t"
               "s_waitcnt vmcnt(0)"
               : "=&v"(r0), "=&v"(r1), "=&v"(r2), "=&v"(r3)
               : "v"(p0), "v"(p1), "v"(p2), "v"(p3) : "memory");
}
__device__ __forceinline__ void l2_atomic_inc(unsigned* p) {
  unsigned one = 1u;
  asm volatile("global_atomic_add %0, %1, off" :: "v"(p), "v"(one) : "memory");
}

// __launch_bounds__(512, 2): 8-wave block at 2 waves/SIMD = 1 WG/CU -> allows
// up to 256 VGPRs/wave. R8's identical kernel at the default cap (128) spilled
// wir/acc to scratch (FETCH_SIZE doubled, VALUBusy 44.7->28).
__global__ __launch_bounds__(NTH, 2) void ha_kernel(
    const int* __restrict__ captions, const int* __restrict__ masks,
    const float* __restrict__ embed_W,
    const float* __restrict__ w_Wih, const float* __restrict__ w_Whh,
    const float* __restrict__ w_bih, const float* __restrict__ w_bhh,
    const float* __restrict__ s_Wih, const float* __restrict__ s_Whh,
    const float* __restrict__ s_bih, const float* __restrict__ s_bhh,
    const float* __restrict__ wa_Wk, const float* __restrict__ wa_Wv,
    const float* __restrict__ sa_Wk, const float* __restrict__ sa_Wv,
    float* __restrict__ out, float* __restrict__ ws) {
  cg::grid_group grid = cg::this_grid();
  const int g = blockIdx.x, tid = threadIdx.x;
  const int jj = tid >> 6;                 // wave
  const int c = tid & 63;                  // col (sentence phase)
  const int half = (tid >> 5) & 1;         // word-GEMV half-wave
  const int c2 = tid & 31;                 // word-GEMV col base (cols c2, c2+32)
  const int ks = jj * 2 + half;            // word-GEMV k/E slice (16 slices)

  float* pub = ws + OFF_PUB;
  float* sh_buf = ws + OFF_SH;
  float* hs_buf = ws + OFF_HS;
  float* z_buf = ws + OFF_Z;
  float* ctx_ws = ws + OFF_CTX;
  float* sent_hs = ws + OFF_SHS;
  float* z2_buf = ws + OFF_Z2;
  unsigned* flags = (unsigned*)(ws + OFF_FLG);
  unsigned* cntp = flags + 8192;
  unsigned* tflagA = flags + 8448;
  unsigned* tdataA = flags + 8704;
  unsigned* verdA = flags + 8960;

  // LDS ~161.8 KB (1 WG/CU)
  __shared__ __align__(16) float whh_s[64 * WHP];   // 132 KB, swizzled
  __shared__ __align__(16) float uni[6752];         // hstage|parts|embed|attn union
  __shared__ float bias_s[64];
  __shared__ float c_s[16][8], hown_s[16][8], sc_s[16][8];
  __shared__ unsigned mbits[24];
  __shared__ float soft_s[96], red_s[96];
  __shared__ int ibuf[4];

  // ---- init zeros (before ranking) ----
  {
    int idx = g * NTH + tid;
    if (idx < 2 * kB * kH) sh_buf[idx] = 0.f;
  }
  if (g == 0)
    for (int idx = tid; idx < 9216; idx += NTH) flags[idx] = 0u;
  grid.sync();

  // ---- XCD discovery + ranking ----
  if (tid == 0) {
    unsigned xcc;
    asm volatile("s_getreg_b32 %0, hwreg(20, 0, 32)" : "=s"(xcc));
    xcc &= 7u;
    unsigned slot = atomicAdd(&cntp[xcc * 32], 1u);
    ibuf[0] = (int)xcc; ibuf[1] = (int)slot;
  }
  grid.sync();
  __syncthreads();
  const int myxcc = ibuf[0], myslot = ibuf[1];
  unsigned cnts[8]; int px[9]; px[0] = 0;
  for (int x = 0; x < 8; ++x) { cnts[x] = aloadu(&cntp[x * 32]); px[x + 1] = px[x] + (int)cnts[x]; }
  const int rank = px[myxcc] + myslot;
  const int grp = rank >> 5, r = rank & 31;
  const int B0 = GB * grp;
  bool pure = false;
  for (int x = 0; x < 8; ++x)
    if (px[x] <= grp * 32 && grp * 32 + 32 <= px[x + 1]) pure = true;
  const bool cand = pure && (cnts[myxcc] <= 40u);
  unsigned* myflag = &flags[(grp * GWG + r) * 32];

  auto g_row = [&](int cc) { return (cc >> 4) * kH + 16 * r + (cc & 15); };

  // ---- L2-coherence handshake (bounded; decides l2m per group, no-hang) ----
  unsigned n = 0;
  {
    unsigned* tf = &tflagA[grp * 32];
    unsigned* td = &tdataA[grp * 32];
    int ok = 0;
    if (cand && r == 0 && tid == 0) {
      *td = 0xC0FFEEu;
      asm volatile("s_waitcnt vmcnt(0)" ::: "memory");
      l2_atomic_inc(tf);
    }
    if (cand && tid == 0) {
      for (int it = 0; it < 4096; ++it) {
        if (l2_loadu(tf) >= 1u) { ok = (l2_loadu(td) == 0xC0FFEEu); break; }
        __builtin_amdgcn_s_sleep(2);
      }
    }
    if (tid == 0) {
      astoreu(&verdA[grp * 32 + r], ok ? 1u : 0u);
      asm volatile("s_waitcnt vmcnt(0)" ::: "memory");
      atomicAdd(myflag, 1u);
    }
    n = 1;
    if (tid < GWG) {
      while (aloadu(&flags[(grp * GWG + tid) * 32]) < 1u) __builtin_amdgcn_s_sleep(2);
    }
    __syncthreads();
    if (tid < GWG) red_s[tid] = (float)aloadu(&verdA[grp * 32 + tid]);
    __syncthreads();
    if (tid == 0) {
      int all = 1;
      for (int i = 0; i < GWG; ++i) all &= (red_s[i] != 0.f);
      ibuf[2] = all;
    }
    __syncthreads();
  }
  const bool l2m = (ibuf[2] != 0);

  // ---- mode-dispatched ops ----
  auto mstore1 = [&](float* p, float v) { if (l2m) *p = v; else astore(p, v); };
  auto mload1 = [&](const float* p) { return l2m ? l2_load1(p) : aload1(p); };
  auto mload2 = [&](const float* p) { return l2m ? l2_load2(p) : aload2(p); };
  auto mload8 = [&](const float* p, f4v& a, f4v& b) {
    if (l2m) l2_load8(p, a, b);
    else {
      float2 t0 = aload2(p), t1 = aload2(p + 2), t2 = aload2(p + 4), t3 = aload2(p + 6);
      a = f4v{t0.x, t0.y, t1.x, t1.y}; b = f4v{t2.x, t2.y, t3.x, t3.y};
    }
  };
  auto mload4s = [&](const float* p0, const float* p1, const float* p2, const float* p3,
                     float& r0, float& r1, float& r2, float& r3) {
    if (l2m) l2_load4s(p0, p1, p2, p3, r0, r1, r2, r3);
    else { r0 = aload1(p0); r1 = aload1(p1); r2 = aload1(p2); r3 = aload1(p3); }
  };
  auto arrive = [&]() {
    __syncthreads();   // drains all stores -> visible at coherence point
    if (tid == 0) { if (l2m) l2_atomic_inc(myflag); else atomicAdd(myflag, 1u); }
  };
  auto wait = [&](unsigned nn) {
    if (tid < GWG) {
      const unsigned* fp = &flags[(grp * GWG + tid) * 32];
      if (l2m) { while (l2_loadu(fp) < nn) __builtin_amdgcn_s_sleep(1); }
      else     { while (aloadu(fp) < nn)   __builtin_amdgcn_s_sleep(1); }
    }
    __syncthreads();
  };

  // ---- per-WG weight staging ----
  for (int idx = tid; idx < 64 * kH; idx += NTH) {
    const int cr = idx >> 9, kk = idx & 511;
    whh_s[cr * WHP + 4 * (((kk >> 2) + 4 * (cr & 1)) & 127) + (kk & 3)] =
        w_Whh[(size_t)g_row(cr) * kH + kk];
  }
  if (tid < 64) bias_s[tid] = w_bih[g_row(tid)] + w_bhh[g_row(tid)];
  if (tid < 128) {
    c_s[tid >> 3][tid & 7] = 0.f; hown_s[tid >> 3][tid & 7] = 0.f; sc_s[tid >> 3][tid & 7] = 0.f;
  }
  for (int idx = tid; idx < 6752; idx += NTH) uni[idx] = 0.f;   // h(0)=0
  // Wih slice for this thread's 2 cols x 16-float E-chunk -> registers (once)
  float4 wir0[4], wir1[4];
  {
    const float* wrA = w_Wih + (size_t)g_row(c2) * kE + 16 * ks;
    const float* wrB = w_Wih + (size_t)g_row(c2 + 32) * kE + 16 * ks;
#pragma unroll
    for (int v = 0; v < 4; ++v) {
      wir0[v] = *(const float4*)&wrA[4 * v];
      wir1[v] = *(const float4*)&wrB[4 * v];
    }
  }
  __syncthreads();

  // ---- stagers ----
  auto stage_hst_pub = [&](const float* slab) {   // slab[rr*128 + b*16 + hcl]
    const int lin = tid * 8, rsm = lin >> 7, rem = lin & 127;
    const int b2 = rem >> 4, kk = (rsm << 4) | (rem & 15);
    f4v a, b4; mload8(slab + lin, a, b4);
    const int ho = kk + 4 * (kk >> 5);
    *(f4v*)&uni[b2 * HSP + ho] = a;
    *(f4v*)&uni[b2 * HSP + ho + 4] = b4;
  };
  auto stage_hst_lin = [&](const float* src) {    // src[b*512 + k]
    const int lin = tid * 8, b2 = lin >> 9, kk = lin & 511;
    f4v a, b4; mload8(src + lin, a, b4);
    const int ho = kk + 4 * (kk >> 5);
    *(f4v*)&uni[b2 * HSP + ho] = a;
    *(f4v*)&uni[b2 * HSP + ho + 4] = b4;
  };
  auto stage_emb = [&](int s2, int t2) {
    const int b2 = tid >> 6, ch = tid & 63;
    const int cap = captions[((B0 + b2) * kS + s2) * kT + t2];
    const float4 v = *(const float4*)&embed_W[(size_t)cap * kE + 4 * ch];
    *(float4*)&uni[EMB0 + b2 * EMP + 4 * ch] = v;
  };
  float xp0[8], xp1[8];
  auto calc_xp = [&]() {   // registers x LDS embed broadcasts only
    const float* eb = &uni[EMB0 + 16 * ks];
#pragma unroll
    for (int b2 = 0; b2 < 8; ++b2) { xp0[b2] = 0.f; xp1[b2] = 0.f; }
#pragma unroll
    for (int v = 0; v < 4; ++v) {
#pragma unroll
      for (int b2 = 0; b2 < 8; ++b2) {
        const float4 ev = *(const float4*)&eb[b2 * EMP + 4 * v];
        xp0[b2] += dot4(wir0[v], ev);
        xp1[b2] += dot4(wir1[v], ev);
      }
    }
  };

  stage_emb(0, 0);
  __syncthreads();
  calc_xp();

  int gstep = 0;
  for (int s = 0; s < kS; ++s) {
    if (tid < 24) {   // pack masks as bits
      const int b2 = tid / 3, w2 = tid % 3;
      unsigned bits = 0u;
      const int base = ((B0 + b2) * kS + s) * kT + 32 * w2;
      for (int j = 0; j < 32; ++j) bits |= (masks[base + j] ? 1u : 0u) << j;
      mbits[b2 * 3 + w2] = bits;
    }
    if (s > 0) stage_hst_pub(pub + ((size_t)((gstep & 1) * NG + grp)) * 4096);
    __syncthreads();

    // ============ word LSTM: 96 steps, one group barrier each ============
    for (int t = 0; t < kT; ++t, ++gstep) {
      float* pubw = pub + ((size_t)(((gstep + 1) & 1) * NG + grp)) * 4096;

      // GEMV: 2 cols x 8 batches per thread, half-wave k-split (80 LDS reads/wave)
      float acc0[8], acc1[8];
#pragma unroll
      for (int b2 = 0; b2 < 8; ++b2) { acc0[b2] = xp0[b2]; acc1[b2] = xp1[b2]; }
      {
        const int swc = 4 * (c2 & 1);
        const float* w0 = &whh_s[c2 * WHP];
        const float* w1 = &whh_s[(c2 + 32) * WHP];
#pragma unroll
        for (int u = 0; u < 8; ++u) {
          const int q = 8 * ks + u;
          const float4 wv0 = *(const float4*)&w0[4 * ((q + swc) & 127)];
          const float4 wv1 = *(const float4*)&w1[4 * ((q + swc) & 127)];
          const int hoff = 4 * q + 4 * (q >> 3);
#pragma unroll
          for (int b2 = 0; b2 < 8; ++b2) {
            const float4 hv = *(const float4*)&uni[b2 * HSP + hoff];
            acc0[b2] += dot4(wv0, hv);
            acc1[b2] += dot4(wv1, hv);
          }
        }
      }
      __syncthreads();   // hstage reads done before parts alias write
      // combine half-waves (k+E slices pair) then write parts[jj][col][b2]
#pragma unroll
      for (int b2 = 0; b2 < 8; ++b2) {
        const float t0 = acc0[b2] + __shfl_xor(acc0[b2], 32);
        const float t1 = acc1[b2] + __shfl_xor(acc1[b2], 32);
        uni[jj * HSP + (c2 + 32 * half) * 9 + b2] = half ? t1 : t0;
      }
      __syncthreads();
      // fused reduce + cell + publish
      float hsv = 0.f;
      if (tid < 128) {
        const int hcl = tid >> 3, b2 = tid & 7;
        float gg4[4];
#pragma unroll
        for (int g2 = 0; g2 < 4; ++g2) {
          const int cc = g2 * 16 + hcl;
          float sum = bias_s[cc];
#pragma unroll
          for (int j = 0; j < 8; ++j) sum += uni[j * HSP + cc * 9 + b2];
          gg4[g2] = sum;
        }
        const float cold = c_s[hcl][b2];
        const float c2v = sigmoidf(gg4[1]) * cold + sigmoidf(gg4[0]) * tanhf(gg4[2]);
        const float h2 = sigmoidf(gg4[3]) * tanhf(c2v);
        const int m = (mbits[b2 * 3 + (t >> 5)] >> (t & 31)) & 1;
        const float cn = m ? c2v : cold;
        const float hn = m ? h2 : hown_s[hcl][b2];
        c_s[hcl][b2] = cn; hown_s[hcl][b2] = hn;
        mstore1(&pubw[r * 128 + b2 * 16 + hcl], hn);
        hsv = m ? h2 : 0.f;
      }
      ++n;
      arrive();
      // ---- cover (runs inside the barrier window) ----
      if (tid < 128) {
        const int hcl = tid >> 3, b2 = tid & 7;
        mstore1(&hs_buf[((size_t)(B0 + b2) * kT + t) * kH + 16 * r + hcl], hsv);
      }
      int ns = s, nt = t + 1; bool have = true;
      if (nt == kT) { nt = 0; ns = s + 1; if (ns == kS) have = false; }
      if (have) stage_emb(ns, nt);
      __syncthreads();
      if (have) calc_xp();
      wait(n);
      stage_hst_pub(pubw);
      __syncthreads();
    }

    ++n; arrive(); wait(n);   // phase 1: hs drained everywhere

    // ============ word attention: z[b,t] ============
    {
      const int ab = r >> 2, t0 = (r & 3) * 24;
      const int bg = B0 + ab;
      for (int halfp = 0; halfp < 2; ++halfp) {
        const int tb = t0 + halfp * 12;
        for (int idx = tid; idx < 12 * 256; idx += NTH) {
          const int pp = idx >> 8, hh2 = (idx & 255) * 2;
          float2 v = mload2(&hs_buf[((size_t)bg * kT + tb + pp) * kH + hh2]);
          *(float2*)&uni[pp * ATP + hh2] = v;
        }
        __syncthreads();
        float dacc[12];
#pragma unroll
        for (int p = 0; p < 12; ++p) dacc[p] = 0.f;
        const float4* __restrict__ wk = (const float4*)(wa_Wk + (size_t)tid * kH);
        for (int k = 0; k < kH / 4; ++k) {
          const float4 w = wk[k];
#pragma unroll
          for (int p = 0; p < 12; ++p)
            dacc[p] += dot4(w, *(const float4*)&uni[p * ATP + 4 * k]);
        }
        const float wv = wa_Wv[tid];
        const int ln = tid & 63, wid = tid >> 6;
#pragma unroll
        for (int p = 0; p < 12; ++p) {
          float v = wv * tanhf(dacc[p]);
          v += __shfl_down(v, 32); v += __shfl_down(v, 16); v += __shfl_down(v, 8);
          v += __shfl_down(v, 4);  v += __shfl_down(v, 2);  v += __shfl_down(v, 1);
          if (ln == 0) red_s[wid * 12 + p] = v;
        }
        __syncthreads();
        if (tid < 12) {
          float sum = 0.f;
#pragma unroll
          for (int w = 0; w < 8; ++w) sum += red_s[w * 12 + tid];
          mstore1(&z_buf[bg * kT + tb + tid], sum);
        }
        __syncthreads();
      }
    }
    ++n; arrive(); wait(n);

    // ============ softmax over T + ctx ============
    if (r < GB) {
      const int b2 = B0 + r;
      if (tid < kT) soft_s[tid] = mload1(&z_buf[b2 * kT + tid]);
      __syncthreads();
      float mx = -1e30f;
      for (int i = 0; i < kT; ++i) mx = fmaxf(mx, soft_s[i]);
      float den = 0.f;
      for (int i = 0; i < kT; ++i) den += expf(soft_s[i] - mx);
      __syncthreads();
      if (tid < kT) soft_s[tid] = expf(soft_s[tid] - mx) / den;
      __syncthreads();
      {
        const int h0 = tid;
        float a0 = 0.f, a1 = 0.f, a2 = 0.f, a3 = 0.f;
        for (int tt = 0; tt < kT; tt += 4) {
          const float* p = &hs_buf[((size_t)b2 * kT + tt) * kH + h0];
          float v0, v1, v2, v3;
          mload4s(p, p + kH, p + 2 * kH, p + 3 * kH, v0, v1, v2, v3);
          a0 += soft_s[tt + 0] * v0;
          a1 += soft_s[tt + 1] * v1;
          a2 += soft_s[tt + 2] * v2;
          a3 += soft_s[tt + 3] * v3;
        }
        mstore1(&ctx_ws[b2 * kH + h0], (a0 + a1) + (a2 + a3));
      }
    }
    ++n; arrive(); wait(n);

    // ============ sentence LSTM (two-pass streamed GEMV) ============
    {
      float acc[8];
#pragma unroll
      for (int b2 = 0; b2 < 8; ++b2) acc[b2] = 0.f;
      stage_hst_lin(ctx_ws + B0 * kH);   // pass A: x = ctx
      __syncthreads();
      {
        const float* wA = s_Wih + (size_t)g_row(c) * kH + 64 * jj;
#pragma unroll 8
        for (int u = 0; u < 16; ++u) {
          const float4 w = *(const float4*)&wA[4 * u];
          const int q = 16 * jj + u;
          const int hoff = 4 * q + 4 * (q >> 3);
#pragma unroll
          for (int b2 = 0; b2 < 8; ++b2)
            acc[b2] += dot4(w, *(const float4*)&uni[b2 * HSP + hoff]);
        }
      }
      __syncthreads();
      stage_hst_lin(sh_buf + (s & 1) * kB * kH + B0 * kH);   // pass B: h = sh
      __syncthreads();
      {
        const float* wB = s_Whh + (size_t)g_row(c) * kH + 64 * jj;
#pragma unroll 8
        for (int u = 0; u < 16; ++u) {
          const float4 w = *(const float4*)&wB[4 * u];
          const int q = 16 * jj + u;
          const int hoff = 4 * q + 4 * (q >> 3);
#pragma unroll
          for (int b2 = 0; b2 < 8; ++b2)
            acc[b2] += dot4(w, *(const float4*)&uni[b2 * HSP + hoff]);
        }
      }
      __syncthreads();
#pragma unroll
      for (int b2 = 0; b2 < 8; ++b2) uni[jj * HSP + c * 9 + b2] = acc[b2];
      __syncthreads();
      if (tid < 128) {
        const int hcl = tid >> 3, b2 = tid & 7;
        float gg4[4];
#pragma unroll
        for (int g2 = 0; g2 < 4; ++g2) {
          const int cc = g2 * 16 + hcl;
          const int row = g_row(cc);
          float sum = s_bih[row] + s_bhh[row];
#pragma unroll
          for (int j = 0; j < 8; ++j) sum += uni[j * HSP + cc * 9 + b2];
          gg4[g2] = sum;
        }
        const float c2v = sigmoidf(gg4[1]) * sc_s[hcl][b2] + sigmoidf(gg4[0]) * tanhf(gg4[2]);
        const float h2 = sigmoidf(gg4[3]) * tanhf(c2v);
        sc_s[hcl][b2] = c2v;
        const int col = 16 * r + hcl;
        mstore1(&sh_buf[((s + 1) & 1) * kB * kH + (B0 + b2) * kH + col], h2);
        mstore1(&sent_hs[((size_t)(B0 + b2) * kS + s) * kH + col], h2);
      }
    }
    ++n; arrive(); wait(n);
  }

  // ============ final attention over S ============
  {
    const int pair0 = r * 6;
    for (int idx = tid; idx < 6 * 256; idx += NTH) {
      const int pp = idx >> 8, hh2 = (idx & 255) * 2;
      const int pr = pair0 + pp;
      float2 v = mload2(&sent_hs[((size_t)(B0 + pr / kS) * kS + pr % kS) * kH + hh2]);
      *(float2*)&uni[pp * ATP + hh2] = v;
    }
    __syncthreads();
    float dacc[6];
#pragma unroll
    for (int p = 0; p < 6; ++p) dacc[p] = 0.f;
    const float4* __restrict__ wk = (const float4*)(sa_Wk + (size_t)tid * kH);
    for (int k = 0; k < kH / 4; ++k) {
      const float4 w = wk[k];
#pragma unroll
      for (int p = 0; p < 6; ++p)
        dacc[p] += dot4(w, *(const float4*)&uni[p * ATP + 4 * k]);
    }
    const float wv = sa_Wv[tid];
    const int ln = tid & 63, wid = tid >> 6;
#pragma unroll
    for (int p = 0; p < 6; ++p) {
      float v = wv * tanhf(dacc[p]);
      v += __shfl_down(v, 32); v += __shfl_down(v, 16); v += __shfl_down(v, 8);
      v += __shfl_down(v, 4);  v += __shfl_down(v, 2);  v += __shfl_down(v, 1);
      if (ln == 0) red_s[wid * 6 + p] = v;
    }
    __syncthreads();
    if (tid < 6) {
      float sum = 0.f;
#pragma unroll
      for (int w = 0; w < 8; ++w) sum += red_s[w * 6 + tid];
      mstore1(&z2_buf[B0 * kS + pair0 + tid], sum);
    }
  }
  ++n; arrive(); wait(n);

  // ============ final softmax + outputs ============
  if (r < GB) {
    const int b2 = B0 + r;
    if (tid < kS) soft_s[tid] = mload1(&z2_buf[b2 * kS + tid]);
    __syncthreads();
    float mx = -1e30f;
    for (int i = 0; i < kS; ++i) mx = fmaxf(mx, soft_s[i]);
    float den = 0.f;
    for (int i = 0; i < kS; ++i) den += expf(soft_s[i] - mx);
    __syncthreads();
    if (tid < kS) {
      const float al = expf(soft_s[tid] - mx) / den;
      soft_s[tid] = al;
      out[kB * kH + b2 * kS + tid] = al;   // alpha
    }
    __syncthreads();
    {
      const int h0 = tid;
      float acc2 = 0.f;
      for (int s2 = 0; s2 < kS; ++s2)
        acc2 += soft_s[s2] * mload1(&sent_hs[((size_t)b2 * kS + s2) * kH + h0]);
      out[b2 * kH + h0] = acc2;   // context
    }
  }
}

extern "C" void kernel_launch(void* const* d_in, const int* in_sizes, int n_in,
                              void* d_out, int out_size, void* d_ws, size_t ws_size,
                              hipStream_t stream) {
  (void)in_sizes; (void)n_in; (void)out_size; (void)ws_size;
  const int* captions = (const int*)d_in[0];
  const int* masks = (const int*)d_in[1];
  const float* embed_W = (const float*)d_in[2];
  const float* w_Wih = (const float*)d_in[3];
  const float* w_Whh = (const float*)d_in[4];
  const float* w_bih = (const float*)d_in[5];
  const float* w_bhh = (const float*)d_in[6];
  const float* s_Wih = (const float*)d_in[7];
  const float* s_Whh = (const float*)d_in[8];
  const float* s_bih = (const float*)d_in[9];
  const float* s_bhh = (const float*)d_in[10];
  const float* wa_Wk = (const float*)d_in[11];
  const float* wa_Wv = (const float*)d_in[12];
  const float* sa_Wk = (const float*)d_in[13];
  const float* sa_Wv = (const float*)d_in[14];
  float* out = (float*)d_out;
  float* ws = (float*)d_ws;

  void* args[] = {&captions, &masks, &embed_W, &w_Wih, &w_Whh, &w_bih, &w_bhh,
                  &s_Wih, &s_Whh, &s_bih, &s_bhh, &wa_Wk, &wa_Wv, &sa_Wk, &sa_Wv,
                  &out, &ws};
  hipLaunchCooperativeKernel((void*)ha_kernel, dim3(NWG), dim3(NTH), args, 0, stream);
}

// Round 11
// 22894.994 us; speedup vs baseline: 1.3120x; 1.3120x over previous
//
#include <hip/hip_runtime.h>
#include <hip/hip_cooperative_groups.h>
#include <math.h>

namespace cg = cooperative_groups;

constexpr int kB = 64, kS = 24, kT = 96, kE = 256, kH = 512, kA = 512;
constexpr int NWG = 256, NTH = 512;
constexpr int NG = 8, GWG = 32, GB = 8;   // groups, WGs/group, batches/group
constexpr int WHP = 516;   // whh LDS row stride
constexpr int HSP = 580;   // hstage/parts row stride
constexpr int EMP = 264;   // embed LDS row stride
constexpr int EMB0 = 4640; // embed base inside uni
constexpr int ATP = 516;   // attention staging stride

// ws layout (floats)
constexpr int OFF_PUB = 0;                       // [2][NG][GWG*128] = 65536
constexpr int OFF_SH  = OFF_PUB + 2 * NG * GWG * 128;
constexpr int OFF_HS  = OFF_SH + 2 * kB * kH;
constexpr int OFF_Z   = OFF_HS + kB * kT * kH;
constexpr int OFF_CTX = OFF_Z + kB * kT;
constexpr int OFF_SHS = OFF_CTX + kB * kH;
constexpr int OFF_Z2  = OFF_SHS + kB * kS * kH;
constexpr int OFF_FLG = (OFF_Z2 + kB * kS + 31) & ~31;
// flag block (uints): [0,8192) flags; [8192,8448) cnt; [8448,8704) tst flag;
// [8704,8960) tst data; [8960,9216) verdicts

typedef float f4v __attribute__((ext_vector_type(4)));

__device__ __forceinline__ float sigmoidf(float x) { return 1.0f / (1.0f + expf(-x)); }
__device__ __forceinline__ float dot4(float4 a, float4 b) {
  return a.x * b.x + a.y * b.y + a.z * b.z + a.w * b.w;
}
// ---- agent-scope (MALL) ops ----
__device__ __forceinline__ float2 aload2(const float* p) {
  unsigned long long u = __hip_atomic_load((const unsigned long long*)p,
                                           __ATOMIC_RELAXED, __HIP_MEMORY_SCOPE_AGENT);
  union { unsigned long long u; float2 f; } cv; cv.u = u;
  return cv.f;
}
__device__ __forceinline__ float aload1(const float* p) {
  return __hip_atomic_load(p, __ATOMIC_RELAXED, __HIP_MEMORY_SCOPE_AGENT);
}
__device__ __forceinline__ void astore(float* p, float v) {
  __hip_atomic_store(p, v, __ATOMIC_RELAXED, __HIP_MEMORY_SCOPE_AGENT);
}
__device__ __forceinline__ unsigned aloadu(const unsigned* p) {
  return __hip_atomic_load(p, __ATOMIC_RELAXED, __HIP_MEMORY_SCOPE_AGENT);
}
__device__ __forceinline__ void astoreu(unsigned* p, unsigned v) {
  __hip_atomic_store(p, v, __ATOMIC_RELAXED, __HIP_MEMORY_SCOPE_AGENT);
}
// ---- L2-scope (intra-XCD) ops: bypass L1 (sc0), served by local L2 ----
__device__ __forceinline__ unsigned l2_loadu(const unsigned* p) {
  unsigned r;
  asm volatile("global_load_dword %0, %1, off sc0\n\ts_waitcnt vmcnt(0)"
               : "=v"(r) : "v"(p) : "memory");
  return r;
}
__device__ __forceinline__ float l2_load1(const float* p) {
  float r;
  asm volatile("global_load_dword %0, %1, off sc0\n\ts_waitcnt vmcnt(0)"
               : "=v"(r) : "v"(p) : "memory");
  return r;
}
__device__ __forceinline__ float2 l2_load2(const float* p) {
  float2 r;
  asm volatile("global_load_dwordx2 %0, %1, off sc0\n\ts_waitcnt vmcnt(0)"
               : "=v"(r) : "v"(p) : "memory");
  return r;
}
__device__ __forceinline__ void l2_load8(const float* p, f4v& a, f4v& b) {
  asm volatile("global_load_dwordx4 %0, %2, off sc0\n\t"
               "global_load_dwordx4 %1, %2, off offset:16 sc0\n\t"
               "s_waitcnt vmcnt(0)"
               : "=&v"(a), "=&v"(b) : "v"(p) : "memory");
}
__device__ __forceinline__ void l2_load4s(const float* p0, const float* p1,
                                          const float* p2, const float* p3,
                                          float& r0, float& r1, float& r2, float& r3) {
  asm volatile("global_load_dword %0, %4, off sc0\n\t"
               "global_load_dword %1, %5, off sc0\n\t"
               "global_load_dword %2, %6, off sc0\n\t"
               "global_load_dword %3, %7, off sc0\n\t"
               "s_waitcnt vmcnt(0)"
               : "=&v"(r0), "=&v"(r1), "=&v"(r2), "=&v"(r3)
               : "v"(p0), "v"(p1), "v"(p2), "v"(p3) : "memory");
}
__device__ __forceinline__ void l2_atomic_inc(unsigned* p) {
  unsigned one = 1u;
  asm volatile("global_atomic_add %0, %1, off" :: "v"(p), "v"(one) : "memory");
}

// R8/R10 lesson: compiler pins 128 VGPRs regardless of launch_bounds; the
// wir-in-register Wih cache (+32 VGPR) spilled to scratch (FETCH doubled,
// VALUBusy 44.7->28). This version keeps the re-blocked GEMV (80 LDS
// reads/wave) but reads Wih from global/L2 per step (R7-proven free at HBM).
__global__ __launch_bounds__(NTH, 2) void ha_kernel(
    const int* __restrict__ captions, const int* __restrict__ masks,
    const float* __restrict__ embed_W,
    const float* __restrict__ w_Wih, const float* __restrict__ w_Whh,
    const float* __restrict__ w_bih, const float* __restrict__ w_bhh,
    const float* __restrict__ s_Wih, const float* __restrict__ s_Whh,
    const float* __restrict__ s_bih, const float* __restrict__ s_bhh,
    const float* __restrict__ wa_Wk, const float* __restrict__ wa_Wv,
    const float* __restrict__ sa_Wk, const float* __restrict__ sa_Wv,
    float* __restrict__ out, float* __restrict__ ws) {
  cg::grid_group grid = cg::this_grid();
  const int g = blockIdx.x, tid = threadIdx.x;
  const int jj = tid >> 6;                 // wave
  const int c = tid & 63;                  // col (sentence phase)
  const int half = (tid >> 5) & 1;         // word-GEMV half-wave
  const int c2 = tid & 31;                 // word-GEMV col base (cols c2, c2+32)
  const int ks = jj * 2 + half;            // word-GEMV k/E slice (16 slices)

  float* pub = ws + OFF_PUB;
  float* sh_buf = ws + OFF_SH;
  float* hs_buf = ws + OFF_HS;
  float* z_buf = ws + OFF_Z;
  float* ctx_ws = ws + OFF_CTX;
  float* sent_hs = ws + OFF_SHS;
  float* z2_buf = ws + OFF_Z2;
  unsigned* flags = (unsigned*)(ws + OFF_FLG);
  unsigned* cntp = flags + 8192;
  unsigned* tflagA = flags + 8448;
  unsigned* tdataA = flags + 8704;
  unsigned* verdA = flags + 8960;

  // LDS ~161.8 KB (1 WG/CU)
  __shared__ __align__(16) float whh_s[64 * WHP];   // 132 KB, swizzled
  __shared__ __align__(16) float uni[6752];         // hstage|parts|embed|attn union
  __shared__ float bias_s[64];
  __shared__ float c_s[16][8], hown_s[16][8], sc_s[16][8];
  __shared__ unsigned mbits[24];
  __shared__ float soft_s[96], red_s[96];
  __shared__ int ibuf[4];

  // ---- init zeros (before ranking) ----
  {
    int idx = g * NTH + tid;
    if (idx < 2 * kB * kH) sh_buf[idx] = 0.f;
  }
  if (g == 0)
    for (int idx = tid; idx < 9216; idx += NTH) flags[idx] = 0u;
  grid.sync();

  // ---- XCD discovery + ranking ----
  if (tid == 0) {
    unsigned xcc;
    asm volatile("s_getreg_b32 %0, hwreg(20, 0, 32)" : "=s"(xcc));
    xcc &= 7u;
    unsigned slot = atomicAdd(&cntp[xcc * 32], 1u);
    ibuf[0] = (int)xcc; ibuf[1] = (int)slot;
  }
  grid.sync();
  __syncthreads();
  const int myxcc = ibuf[0], myslot = ibuf[1];
  unsigned cnts[8]; int px[9]; px[0] = 0;
  for (int x = 0; x < 8; ++x) { cnts[x] = aloadu(&cntp[x * 32]); px[x + 1] = px[x] + (int)cnts[x]; }
  const int rank = px[myxcc] + myslot;
  const int grp = rank >> 5, r = rank & 31;
  const int B0 = GB * grp;
  bool pure = false;
  for (int x = 0; x < 8; ++x)
    if (px[x] <= grp * 32 && grp * 32 + 32 <= px[x + 1]) pure = true;
  const bool cand = pure && (cnts[myxcc] <= 40u);
  unsigned* myflag = &flags[(grp * GWG + r) * 32];

  auto g_row = [&](int cc) { return (cc >> 4) * kH + 16 * r + (cc & 15); };

  // ---- L2-coherence handshake (bounded; decides l2m per group, no-hang) ----
  unsigned n = 0;
  {
    unsigned* tf = &tflagA[grp * 32];
    unsigned* td = &tdataA[grp * 32];
    int ok = 0;
    if (cand && r == 0 && tid == 0) {
      *td = 0xC0FFEEu;
      asm volatile("s_waitcnt vmcnt(0)" ::: "memory");
      l2_atomic_inc(tf);
    }
    if (cand && tid == 0) {
      for (int it = 0; it < 4096; ++it) {
        if (l2_loadu(tf) >= 1u) { ok = (l2_loadu(td) == 0xC0FFEEu); break; }
        __builtin_amdgcn_s_sleep(2);
      }
    }
    if (tid == 0) {
      astoreu(&verdA[grp * 32 + r], ok ? 1u : 0u);
      asm volatile("s_waitcnt vmcnt(0)" ::: "memory");
      atomicAdd(myflag, 1u);
    }
    n = 1;
    if (tid < GWG) {
      while (aloadu(&flags[(grp * GWG + tid) * 32]) < 1u) __builtin_amdgcn_s_sleep(2);
    }
    __syncthreads();
    if (tid < GWG) red_s[tid] = (float)aloadu(&verdA[grp * 32 + tid]);
    __syncthreads();
    if (tid == 0) {
      int all = 1;
      for (int i = 0; i < GWG; ++i) all &= (red_s[i] != 0.f);
      ibuf[2] = all;
    }
    __syncthreads();
  }
  const bool l2m = (ibuf[2] != 0);

  // ---- mode-dispatched ops ----
  auto mstore1 = [&](float* p, float v) { if (l2m) *p = v; else astore(p, v); };
  auto mload1 = [&](const float* p) { return l2m ? l2_load1(p) : aload1(p); };
  auto mload2 = [&](const float* p) { return l2m ? l2_load2(p) : aload2(p); };
  auto mload8 = [&](const float* p, f4v& a, f4v& b) {
    if (l2m) l2_load8(p, a, b);
    else {
      float2 t0 = aload2(p), t1 = aload2(p + 2), t2 = aload2(p + 4), t3 = aload2(p + 6);
      a = f4v{t0.x, t0.y, t1.x, t1.y}; b = f4v{t2.x, t2.y, t3.x, t3.y};
    }
  };
  auto mload4s = [&](const float* p0, const float* p1, const float* p2, const float* p3,
                     float& r0, float& r1, float& r2, float& r3) {
    if (l2m) l2_load4s(p0, p1, p2, p3, r0, r1, r2, r3);
    else { r0 = aload1(p0); r1 = aload1(p1); r2 = aload1(p2); r3 = aload1(p3); }
  };
  auto arrive = [&]() {
    __syncthreads();   // drains all stores -> visible at coherence point
    if (tid == 0) { if (l2m) l2_atomic_inc(myflag); else atomicAdd(myflag, 1u); }
  };
  auto wait = [&](unsigned nn) {
    if (tid < GWG) {
      const unsigned* fp = &flags[(grp * GWG + tid) * 32];
      if (l2m) { while (l2_loadu(fp) < nn) __builtin_amdgcn_s_sleep(1); }
      else     { while (aloadu(fp) < nn)   __builtin_amdgcn_s_sleep(1); }
    }
    __syncthreads();
  };

  // ---- per-WG weight staging ----
  for (int idx = tid; idx < 64 * kH; idx += NTH) {
    const int cr = idx >> 9, kk = idx & 511;
    whh_s[cr * WHP + 4 * (((kk >> 2) + 4 * (cr & 1)) & 127) + (kk & 3)] =
        w_Whh[(size_t)g_row(cr) * kH + kk];
  }
  if (tid < 64) bias_s[tid] = w_bih[g_row(tid)] + w_bhh[g_row(tid)];
  if (tid < 128) {
    c_s[tid >> 3][tid & 7] = 0.f; hown_s[tid >> 3][tid & 7] = 0.f; sc_s[tid >> 3][tid & 7] = 0.f;
  }
  for (int idx = tid; idx < 6752; idx += NTH) uni[idx] = 0.f;   // h(0)=0
  __syncthreads();

  // ---- stagers ----
  auto stage_hst_pub = [&](const float* slab) {   // slab[rr*128 + b*16 + hcl]
    const int lin = tid * 8, rsm = lin >> 7, rem = lin & 127;
    const int b2 = rem >> 4, kk = (rsm << 4) | (rem & 15);
    f4v a, b4; mload8(slab + lin, a, b4);
    const int ho = kk + 4 * (kk >> 5);
    *(f4v*)&uni[b2 * HSP + ho] = a;
    *(f4v*)&uni[b2 * HSP + ho + 4] = b4;
  };
  auto stage_hst_lin = [&](const float* src) {    // src[b*512 + k]
    const int lin = tid * 8, b2 = lin >> 9, kk = lin & 511;
    f4v a, b4; mload8(src + lin, a, b4);
    const int ho = kk + 4 * (kk >> 5);
    *(f4v*)&uni[b2 * HSP + ho] = a;
    *(f4v*)&uni[b2 * HSP + ho + 4] = b4;
  };
  auto stage_emb = [&](int s2, int t2) {
    const int b2 = tid >> 6, ch = tid & 63;
    const int cap = captions[((B0 + b2) * kS + s2) * kT + t2];
    const float4 v = *(const float4*)&embed_W[(size_t)cap * kE + 4 * ch];
    *(float4*)&uni[EMB0 + b2 * EMP + 4 * ch] = v;
  };
  // xp for 2 cols x 8 batches; Wih read from global (L2-resident slice,
  // R7-proven no-HBM-cost) -> no wir register cache, no spill.
  float xp0[8], xp1[8];
  auto calc_xp = [&]() {
    const float* wrA = w_Wih + (size_t)g_row(c2) * kE + 16 * ks;
    const float* wrB = w_Wih + (size_t)g_row(c2 + 32) * kE + 16 * ks;
    const float* eb = &uni[EMB0 + 16 * ks];
#pragma unroll
    for (int b2 = 0; b2 < 8; ++b2) { xp0[b2] = 0.f; xp1[b2] = 0.f; }
#pragma unroll
    for (int v = 0; v < 4; ++v) {
      const float4 wA = *(const float4*)&wrA[4 * v];
      const float4 wB = *(const float4*)&wrB[4 * v];
#pragma unroll
      for (int b2 = 0; b2 < 8; ++b2) {
        const float4 ev = *(const float4*)&eb[b2 * EMP + 4 * v];
        xp0[b2] += dot4(wA, ev);
        xp1[b2] += dot4(wB, ev);
      }
    }
  };

  stage_emb(0, 0);
  __syncthreads();
  calc_xp();

  int gstep = 0;
  for (int s = 0; s < kS; ++s) {
    if (tid < 24) {   // pack masks as bits
      const int b2 = tid / 3, w2 = tid % 3;
      unsigned bits = 0u;
      const int base = ((B0 + b2) * kS + s) * kT + 32 * w2;
      for (int j = 0; j < 32; ++j) bits |= (masks[base + j] ? 1u : 0u) << j;
      mbits[b2 * 3 + w2] = bits;
    }
    if (s > 0) stage_hst_pub(pub + ((size_t)((gstep & 1) * NG + grp)) * 4096);
    __syncthreads();

    // ============ word LSTM: 96 steps, one group barrier each ============
    for (int t = 0; t < kT; ++t, ++gstep) {
      float* pubw = pub + ((size_t)(((gstep + 1) & 1) * NG + grp)) * 4096;

      // GEMV: 2 cols x 8 batches per thread, half-wave k-split (80 LDS reads/wave)
      float acc0[8], acc1[8];
#pragma unroll
      for (int b2 = 0; b2 < 8; ++b2) { acc0[b2] = xp0[b2]; acc1[b2] = xp1[b2]; }
      {
        const int swc = 4 * (c2 & 1);
        const float* w0 = &whh_s[c2 * WHP];
        const float* w1 = &whh_s[(c2 + 32) * WHP];
#pragma unroll
        for (int u = 0; u < 8; ++u) {
          const int q = 8 * ks + u;
          const float4 wv0 = *(const float4*)&w0[4 * ((q + swc) & 127)];
          const float4 wv1 = *(const float4*)&w1[4 * ((q + swc) & 127)];
          const int hoff = 4 * q + 4 * (q >> 3);
#pragma unroll
          for (int b2 = 0; b2 < 8; ++b2) {
            const float4 hv = *(const float4*)&uni[b2 * HSP + hoff];
            acc0[b2] += dot4(wv0, hv);
            acc1[b2] += dot4(wv1, hv);
          }
        }
      }
      __syncthreads();   // hstage reads done before parts alias write
      // combine half-waves (k+E slices pair) then write parts[jj][col][b2]
#pragma unroll
      for (int b2 = 0; b2 < 8; ++b2) {
        const float t0 = acc0[b2] + __shfl_xor(acc0[b2], 32);
        const float t1 = acc1[b2] + __shfl_xor(acc1[b2], 32);
        uni[jj * HSP + (c2 + 32 * half) * 9 + b2] = half ? t1 : t0;
      }
      __syncthreads();
      // fused reduce + cell + publish
      float hsv = 0.f;
      if (tid < 128) {
        const int hcl = tid >> 3, b2 = tid & 7;
        float gg4[4];
#pragma unroll
        for (int g2 = 0; g2 < 4; ++g2) {
          const int cc = g2 * 16 + hcl;
          float sum = bias_s[cc];
#pragma unroll
          for (int j = 0; j < 8; ++j) sum += uni[j * HSP + cc * 9 + b2];
          gg4[g2] = sum;
        }
        const float cold = c_s[hcl][b2];
        const float c2v = sigmoidf(gg4[1]) * cold + sigmoidf(gg4[0]) * tanhf(gg4[2]);
        const float h2 = sigmoidf(gg4[3]) * tanhf(c2v);
        const int m = (mbits[b2 * 3 + (t >> 5)] >> (t & 31)) & 1;
        const float cn = m ? c2v : cold;
        const float hn = m ? h2 : hown_s[hcl][b2];
        c_s[hcl][b2] = cn; hown_s[hcl][b2] = hn;
        mstore1(&pubw[r * 128 + b2 * 16 + hcl], hn);
        hsv = m ? h2 : 0.f;
      }
      ++n;
      arrive();
      // ---- cover (runs inside the barrier window) ----
      if (tid < 128) {
        const int hcl = tid >> 3, b2 = tid & 7;
        mstore1(&hs_buf[((size_t)(B0 + b2) * kT + t) * kH + 16 * r + hcl], hsv);
      }
      int ns = s, nt = t + 1; bool have = true;
      if (nt == kT) { nt = 0; ns = s + 1; if (ns == kS) have = false; }
      if (have) stage_emb(ns, nt);
      __syncthreads();
      if (have) calc_xp();
      wait(n);
      stage_hst_pub(pubw);
      __syncthreads();
    }

    ++n; arrive(); wait(n);   // phase 1: hs drained everywhere

    // ============ word attention: z[b,t] ============
    {
      const int ab = r >> 2, t0 = (r & 3) * 24;
      const int bg = B0 + ab;
      for (int halfp = 0; halfp < 2; ++halfp) {
        const int tb = t0 + halfp * 12;
        for (int idx = tid; idx < 12 * 256; idx += NTH) {
          const int pp = idx >> 8, hh2 = (idx & 255) * 2;
          float2 v = mload2(&hs_buf[((size_t)bg * kT + tb + pp) * kH + hh2]);
          *(float2*)&uni[pp * ATP + hh2] = v;
        }
        __syncthreads();
        float dacc[12];
#pragma unroll
        for (int p = 0; p < 12; ++p) dacc[p] = 0.f;
        const float4* __restrict__ wk = (const float4*)(wa_Wk + (size_t)tid * kH);
        for (int k = 0; k < kH / 4; ++k) {
          const float4 w = wk[k];
#pragma unroll
          for (int p = 0; p < 12; ++p)
            dacc[p] += dot4(w, *(const float4*)&uni[p * ATP + 4 * k]);
        }
        const float wv = wa_Wv[tid];
        const int ln = tid & 63, wid = tid >> 6;
#pragma unroll
        for (int p = 0; p < 12; ++p) {
          float v = wv * tanhf(dacc[p]);
          v += __shfl_down(v, 32); v += __shfl_down(v, 16); v += __shfl_down(v, 8);
          v += __shfl_down(v, 4);  v += __shfl_down(v, 2);  v += __shfl_down(v, 1);
          if (ln == 0) red_s[wid * 12 + p] = v;
        }
        __syncthreads();
        if (tid < 12) {
          float sum = 0.f;
#pragma unroll
          for (int w = 0; w < 8; ++w) sum += red_s[w * 12 + tid];
          mstore1(&z_buf[bg * kT + tb + tid], sum);
        }
        __syncthreads();
      }
    }
    ++n; arrive(); wait(n);

    // ============ softmax over T + ctx ============
    if (r < GB) {
      const int b2 = B0 + r;
      if (tid < kT) soft_s[tid] = mload1(&z_buf[b2 * kT + tid]);
      __syncthreads();
      float mx = -1e30f;
      for (int i = 0; i < kT; ++i) mx = fmaxf(mx, soft_s[i]);
      float den = 0.f;
      for (int i = 0; i < kT; ++i) den += expf(soft_s[i] - mx);
      __syncthreads();
      if (tid < kT) soft_s[tid] = expf(soft_s[tid] - mx) / den;
      __syncthreads();
      {
        const int h0 = tid;
        float a0 = 0.f, a1 = 0.f, a2 = 0.f, a3 = 0.f;
        for (int tt = 0; tt < kT; tt += 4) {
          const float* p = &hs_buf[((size_t)b2 * kT + tt) * kH + h0];
          float v0, v1, v2, v3;
          mload4s(p, p + kH, p + 2 * kH, p + 3 * kH, v0, v1, v2, v3);
          a0 += soft_s[tt + 0] * v0;
          a1 += soft_s[tt + 1] * v1;
          a2 += soft_s[tt + 2] * v2;
          a3 += soft_s[tt + 3] * v3;
        }
        mstore1(&ctx_ws[b2 * kH + h0], (a0 + a1) + (a2 + a3));
      }
    }
    ++n; arrive(); wait(n);

    // ============ sentence LSTM (two-pass streamed GEMV) ============
    {
      float acc[8];
#pragma unroll
      for (int b2 = 0; b2 < 8; ++b2) acc[b2] = 0.f;
      stage_hst_lin(ctx_ws + B0 * kH);   // pass A: x = ctx
      __syncthreads();
      {
        const float* wA = s_Wih + (size_t)g_row(c) * kH + 64 * jj;
#pragma unroll 8
        for (int u = 0; u < 16; ++u) {
          const float4 w = *(const float4*)&wA[4 * u];
          const int q = 16 * jj + u;
          const int hoff = 4 * q + 4 * (q >> 3);
#pragma unroll
          for (int b2 = 0; b2 < 8; ++b2)
            acc[b2] += dot4(w, *(const float4*)&uni[b2 * HSP + hoff]);
        }
      }
      __syncthreads();
      stage_hst_lin(sh_buf + (s & 1) * kB * kH + B0 * kH);   // pass B: h = sh
      __syncthreads();
      {
        const float* wB = s_Whh + (size_t)g_row(c) * kH + 64 * jj;
#pragma unroll 8
        for (int u = 0; u < 16; ++u) {
          const float4 w = *(const float4*)&wB[4 * u];
          const int q = 16 * jj + u;
          const int hoff = 4 * q + 4 * (q >> 3);
#pragma unroll
          for (int b2 = 0; b2 < 8; ++b2)
            acc[b2] += dot4(w, *(const float4*)&uni[b2 * HSP + hoff]);
        }
      }
      __syncthreads();
#pragma unroll
      for (int b2 = 0; b2 < 8; ++b2) uni[jj * HSP + c * 9 + b2] = acc[b2];
      __syncthreads();
      if (tid < 128) {
        const int hcl = tid >> 3, b2 = tid & 7;
        float gg4[4];
#pragma unroll
        for (int g2 = 0; g2 < 4; ++g2) {
          const int cc = g2 * 16 + hcl;
          const int row = g_row(cc);
          float sum = s_bih[row] + s_bhh[row];
#pragma unroll
          for (int j = 0; j < 8; ++j) sum += uni[j * HSP + cc * 9 + b2];
          gg4[g2] = sum;
        }
        const float c2v = sigmoidf(gg4[1]) * sc_s[hcl][b2] + sigmoidf(gg4[0]) * tanhf(gg4[2]);
        const float h2 = sigmoidf(gg4[3]) * tanhf(c2v);
        sc_s[hcl][b2] = c2v;
        const int col = 16 * r + hcl;
        mstore1(&sh_buf[((s + 1) & 1) * kB * kH + (B0 + b2) * kH + col], h2);
        mstore1(&sent_hs[((size_t)(B0 + b2) * kS + s) * kH + col], h2);
      }
    }
    ++n; arrive(); wait(n);
  }

  // ============ final attention over S ============
  {
    const int pair0 = r * 6;
    for (int idx = tid; idx < 6 * 256; idx += NTH) {
      const int pp = idx >> 8, hh2 = (idx & 255) * 2;
      const int pr = pair0 + pp;
      float2 v = mload2(&sent_hs[((size_t)(B0 + pr / kS) * kS + pr % kS) * kH + hh2]);
      *(float2*)&uni[pp * ATP + hh2] = v;
    }
    __syncthreads();
    float dacc[6];
#pragma unroll
    for (int p = 0; p < 6; ++p) dacc[p] = 0.f;
    const float4* __restrict__ wk = (const float4*)(sa_Wk + (size_t)tid * kH);
    for (int k = 0; k < kH / 4; ++k) {
      const float4 w = wk[k];
#pragma unroll
      for (int p = 0; p < 6; ++p)
        dacc[p] += dot4(w, *(const float4*)&uni[p * ATP + 4 * k]);
    }
    const float wv = sa_Wv[tid];
    const int ln = tid & 63, wid = tid >> 6;
#pragma unroll
    for (int p = 0; p < 6; ++p) {
      float v = wv * tanhf(dacc[p]);
      v += __shfl_down(v, 32); v += __shfl_down(v, 16); v += __shfl_down(v, 8);
      v += __shfl_down(v, 4);  v += __shfl_down(v, 2);  v += __shfl_down(v, 1);
      if (ln == 0) red_s[wid * 6 + p] = v;
    }
    __syncthreads();
    if (tid < 6) {
      float sum = 0.f;
#pragma unroll
      for (int w = 0; w < 8; ++w) sum += red_s[w * 6 + tid];
      mstore1(&z2_buf[B0 * kS + pair0 + tid], sum);
    }
  }
  ++n; arrive(); wait(n);

  // ============ final softmax + outputs ============
  if (r < GB) {
    const int b2 = B0 + r;
    if (tid < kS) soft_s[tid] = mload1(&z2_buf[b2 * kS + tid]);
    __syncthreads();
    float mx = -1e30f;
    for (int i = 0; i < kS; ++i) mx = fmaxf(mx, soft_s[i]);
    float den = 0.f;
    for (int i = 0; i < kS; ++i) den += expf(soft_s[i] - mx);
    __syncthreads();
    if (tid < kS) {
      const float al = expf(soft_s[tid] - mx) / den;
      soft_s[tid] = al;
      out[kB * kH + b2 * kS + tid] = al;   // alpha
    }
    __syncthreads();
    {
      const int h0 = tid;
      float acc2 = 0.f;
      for (int s2 = 0; s2 < kS; ++s2)
        acc2 += soft_s[s2] * mload1(&sent_hs[((size_t)b2 * kS + s2) * kH + h0]);
      out[b2 * kH + h0] = acc2;   // context
    }
  }
}

extern "C" void kernel_launch(void* const* d_in, const int* in_sizes, int n_in,
                              void* d_out, int out_size, void* d_ws, size_t ws_size,
                              hipStream_t stream) {
  (void)in_sizes; (void)n_in; (void)out_size; (void)ws_size;
  const int* captions = (const int*)d_in[0];
  const int* masks = (const int*)d_in[1];
  const float* embed_W = (const float*)d_in[2];
  const float* w_Wih = (const float*)d_in[3];
  const float* w_Whh = (const float*)d_in[4];
  const float* w_bih = (const float*)d_in[5];
  const float* w_bhh = (const float*)d_in[6];
  const float* s_Wih = (const float*)d_in[7];
  const float* s_Whh = (const float*)d_in[8];
  const float* s_bih = (const float*)d_in[9];
  const float* s_bhh = (const float*)d_in[10];
  const float* wa_Wk = (const float*)d_in[11];
  const float* wa_Wv = (const float*)d_in[12];
  const float* sa_Wk = (const float*)d_in[13];
  const float* sa_Wv = (const float*)d_in[14];
  float* out = (float*)d_out;
  float* ws = (float*)d_ws;

  void* args[] = {&captions, &masks, &embed_W, &w_Wih, &w_Whh, &w_bih, &w_bhh,
                  &s_Wih, &s_Whh, &s_bih, &s_bhh, &wa_Wk, &wa_Wv, &sa_Wk, &sa_Wv,
                  &out, &ws};
  hipLaunchCooperativeKernel((void*)ha_kernel, dim3(NWG), dim3(NTH), args, 0, stream);
}